// Round 5
// baseline (148.133 us; speedup 1.0000x reference)
//
#include <hip/hip_runtime.h>

#define NPTS 512
#define BLOCK 256
#define XPS 68   // xp row stride (dwords): mult of 4 (16B rows), mod 32 = 4 staggers banks

// ---------------------------------------------------------------------------
// Kernel 1: per-batch weighted moments — ONE WAVE PER BATCH, NO BARRIERS.
//
// R2–R4 lessons baked in:
//  - R3: >=96B-per-lane strides thrash L1 (6x line inflation). Here lane L
//    reads point p = L + 64k as three b32 at 12-B lane stride: each
//    wave-instr covers a dense 768-B window; the x/y/z triplet consumes
//    lines while L1-hot. No LDS staging needed at all.
//  - R2: shuffle butterflies are a DS storm. Keep the cheap transpose-reduce
//    (16 ds_write_b32 + 4 ds_read_b128 + 2 shfl_xor, all 2-way aliasing = free).
//  - R4: block-wide barriers convoy the waves and serialize mem/DS/VALU
//    phases. Each wave owns its batch end-to-end; intra-wave LDS ops are
//    in-order, so ZERO __syncthreads.
// ---------------------------------------------------------------------------
__global__ __launch_bounds__(BLOCK) void wproc_moments(
    const float* __restrict__ src,
    const float* __restrict__ tgt,
    const float* __restrict__ wts,
    float* __restrict__ ws)
{
    const int wave = threadIdx.x >> 6;
    const int lane = threadIdx.x & 63;
    const int b = blockIdx.x * 4 + wave;   // grid = B/4 exact (B=8192)

    const float* sb = src + (size_t)b * (NPTS * 3);
    const float* tb = tgt + (size_t)b * (NPTS * 3);
    const float* wb = wts + (size_t)b * NPTS;

    // [W, m_s(3), m_t(3), M(9) row-major M_ij = sum w*src_i*tgt_j]
    float acc[16];
    #pragma unroll
    for (int i = 0; i < 16; ++i) acc[i] = 0.f;

    #pragma unroll
    for (int k = 0; k < 8; ++k) {
        const int p = lane + 64 * k;
        float w = wb[p];
        w = (w < 0.f) ? 0.f : w;  // WEIGHT_THRESHOLD = 0.0
        const float sx = sb[3 * p + 0], sy = sb[3 * p + 1], sz = sb[3 * p + 2];
        const float tx = tb[3 * p + 0], ty = tb[3 * p + 1], tz = tb[3 * p + 2];
        acc[0] += w;
        acc[1] += w * sx; acc[2] += w * sy; acc[3] += w * sz;
        acc[4] += w * tx; acc[5] += w * ty; acc[6] += w * tz;
        const float wsx = w * sx, wsy = w * sy, wsz = w * sz;
        acc[7]  += wsx * tx; acc[8]  += wsx * ty; acc[9]  += wsx * tz;
        acc[10] += wsy * tx; acc[11] += wsy * ty; acc[12] += wsy * tz;
        acc[13] += wsz * tx; acc[14] += wsz * ty; acc[15] += wsz * tz;
    }

    // ---- wave-private transpose-reduce (no block barrier needed) ----
    __shared__ float xp[4][16][XPS];
    #pragma unroll
    for (int m = 0; m < 16; ++m) xp[wave][m][lane] = acc[m];
    // intra-wave DS ops complete in order; compiler inserts lgkmcnt before reads

    {
        const int m = lane & 15, q = lane >> 4;
        const float4* row = (const float4*)&xp[wave][m][0] + 4 * q;
        float4 a0 = row[0], a1 = row[1], a2 = row[2], a3 = row[3];
        a0.x += a1.x; a0.y += a1.y; a0.z += a1.z; a0.w += a1.w;
        a2.x += a3.x; a2.y += a3.y; a2.z += a3.z; a2.w += a3.w;
        a0.x += a2.x; a0.y += a2.y; a0.z += a2.z; a0.w += a2.w;
        float v = (a0.x + a0.y) + (a0.z + a0.w);
        v += __shfl_xor(v, 16, 64);
        v += __shfl_xor(v, 32, 64);
        if (q == 0) ws[(size_t)b * 16 + m] = v;
    }
}

// ---------------------------------------------------------------------------
// Kernel 2: per-batch 3x3 Procrustes solve, one lane per batch (~2 us total;
// fusing it into the moments wave would put ~10 us of f64 VALU on the hot
// path — keep separate).
//
// Algebra: with T = sum(w)+eps:
//   src_c = m_s/T, tgt_c = m_t/T
//   H = M/T - (2 - W/T) * src_c * tgt_c^T   (exact expansion of centered cov)
// SVD-free rotation: Jacobi eigendecomp of A = H^T H -> V; v3 := v1 x v2,
// u_i = H v_i (Gram-Schmidt), u3 := u1 x u2; R = V U^T. The cross products
// force det(U)=det(V)=+1, reproducing the reference's diag(1,1,sign(det))
// reflection correction exactly.
// ---------------------------------------------------------------------------
__global__ __launch_bounds__(BLOCK) void wproc_solve(
    const float* __restrict__ ws,
    float* __restrict__ out,
    int B)
{
    const int b = blockIdx.x * BLOCK + threadIdx.x;
    if (b >= B) return;

    double m[16];
    #pragma unroll
    for (int i = 0; i < 16; ++i) m[i] = (double)ws[(size_t)b * 16 + i];

    const double T = m[0] + 1e-5;       // sum(w) + EPS
    const double f = 2.0 - m[0] / T;
    const double cs[3] = { m[1] / T, m[2] / T, m[3] / T };
    const double ct[3] = { m[4] / T, m[5] / T, m[6] / T };
    double H[3][3];
    for (int i = 0; i < 3; ++i)
        for (int j = 0; j < 3; ++j)
            H[i][j] = m[7 + i * 3 + j] / T - f * cs[i] * ct[j];

    // A = H^T H (symmetric PSD)
    double A[3][3];
    for (int i = 0; i < 3; ++i)
        for (int j = 0; j < 3; ++j)
            A[i][j] = H[0][i] * H[0][j] + H[1][i] * H[1][j] + H[2][i] * H[2][j];

    // Jacobi eigendecomposition: A = V diag V^T
    double V[3][3] = { {1, 0, 0}, {0, 1, 0}, {0, 0, 1} };
    for (int sweep = 0; sweep < 5; ++sweep) {
        for (int pair = 0; pair < 3; ++pair) {
            const int p = (pair == 2) ? 1 : 0;
            const int q = (pair == 0) ? 1 : 2;
            const double apq = A[p][q];
            if (apq == 0.0) continue;
            const double theta = (A[q][q] - A[p][p]) / (2.0 * apq);
            const double tt = ((theta >= 0.0) ? 1.0 : -1.0)
                            / (fabs(theta) + sqrt(theta * theta + 1.0));
            const double c = 1.0 / sqrt(tt * tt + 1.0);
            const double sn = tt * c;
            for (int k = 0; k < 3; ++k) {  // A <- A G
                const double akp = A[k][p], akq = A[k][q];
                A[k][p] = c * akp - sn * akq;
                A[k][q] = sn * akp + c * akq;
            }
            for (int k = 0; k < 3; ++k) {  // A <- G^T A
                const double apk = A[p][k], aqk = A[q][k];
                A[p][k] = c * apk - sn * aqk;
                A[q][k] = sn * apk + c * aqk;
            }
            for (int k = 0; k < 3; ++k) {  // V <- V G
                const double vkp = V[k][p], vkq = V[k][q];
                V[k][p] = c * vkp - sn * vkq;
                V[k][q] = sn * vkp + c * vkq;
            }
        }
    }

    // sort eigenpairs descending
    const double lam[3] = { A[0][0], A[1][1], A[2][2] };
    int i0 = 0, i1 = 1, i2 = 2;
    if (lam[i0] < lam[i1]) { int tmp = i0; i0 = i1; i1 = tmp; }
    if (lam[i0] < lam[i2]) { int tmp = i0; i0 = i2; i2 = tmp; }
    if (lam[i1] < lam[i2]) { int tmp = i1; i1 = i2; i2 = tmp; }

    const double v1[3] = { V[0][i0], V[1][i0], V[2][i0] };
    const double v2[3] = { V[0][i1], V[1][i1], V[2][i1] };
    const double v3[3] = { v1[1] * v2[2] - v1[2] * v2[1],
                           v1[2] * v2[0] - v1[0] * v2[2],
                           v1[0] * v2[1] - v1[1] * v2[0] };

    double u1[3], u2[3], u3[3];
    for (int i = 0; i < 3; ++i)
        u1[i] = H[i][0] * v1[0] + H[i][1] * v1[1] + H[i][2] * v1[2];
    double n1 = sqrt(u1[0] * u1[0] + u1[1] * u1[1] + u1[2] * u1[2]);
    n1 = (n1 > 1e-30) ? n1 : 1e-30;
    for (int i = 0; i < 3; ++i) u1[i] /= n1;

    for (int i = 0; i < 3; ++i)
        u2[i] = H[i][0] * v2[0] + H[i][1] * v2[1] + H[i][2] * v2[2];
    const double d12 = u1[0] * u2[0] + u1[1] * u2[1] + u1[2] * u2[2];
    for (int i = 0; i < 3; ++i) u2[i] -= d12 * u1[i];
    double n2 = sqrt(u2[0] * u2[0] + u2[1] * u2[1] + u2[2] * u2[2]);
    n2 = (n2 > 1e-30) ? n2 : 1e-30;
    for (int i = 0; i < 3; ++i) u2[i] /= n2;

    u3[0] = u1[1] * u2[2] - u1[2] * u2[1];
    u3[1] = u1[2] * u2[0] - u1[0] * u2[2];
    u3[2] = u1[0] * u2[1] - u1[1] * u2[0];

    double R[3][3];
    for (int i = 0; i < 3; ++i)
        for (int j = 0; j < 3; ++j)
            R[i][j] = v1[i] * u1[j] + v2[i] * u2[j] + v3[i] * u3[j];

    double tv[3];
    for (int i = 0; i < 3; ++i)
        tv[i] = ct[i] - (R[i][0] * cs[0] + R[i][1] * cs[1] + R[i][2] * cs[2]);

    float* outR = out + (size_t)b * 9;
    for (int i = 0; i < 3; ++i)
        for (int j = 0; j < 3; ++j)
            outR[i * 3 + j] = (float)R[i][j];
    float* outT = out + (size_t)B * 9 + (size_t)b * 3;
    for (int i = 0; i < 3; ++i) outT[i] = (float)tv[i];
}

extern "C" void kernel_launch(void* const* d_in, const int* in_sizes, int n_in,
                              void* d_out, int out_size, void* d_ws, size_t ws_size,
                              hipStream_t stream) {
    const float* src = (const float*)d_in[0];
    const float* tgt = (const float*)d_in[1];
    const float* wts = (const float*)d_in[2];
    float* out = (float*)d_out;
    float* ws = (float*)d_ws;   // 16 floats per batch = 512 KB
    const int B = out_size / 12;  // 9 (R) + 3 (t) floats per batch; B=8192

    wproc_moments<<<B / 4, BLOCK, 0, stream>>>(src, tgt, wts, ws);
    wproc_solve<<<(B + BLOCK - 1) / BLOCK, BLOCK, 0, stream>>>(ws, out, B);
}